// Round 4
// baseline (370.487 us; speedup 1.0000x reference)
//
#include <hip/hip_runtime.h>
#include <math.h>

#define IN_C 64
#define OUT_C 16

typedef float f4 __attribute__((ext_vector_type(4)));   // native vec for NT builtins

// ---------------------------------------------------------------------------
// Kernel 1: h = x @ W_lin + b_lin      [N,64] x [64,16] -> [N,16]
// x is single-use: non-temporal loads keep L2 clean for the edge kernel.
// ---------------------------------------------------------------------------
__global__ __launch_bounds__(256) void node_linear_kernel(
    const float* __restrict__ x, const float* __restrict__ W_lin,
    const float* __restrict__ b_lin, float* __restrict__ h, int N)
{
    __shared__ float sW[IN_C * OUT_C];   // 4 KB
    __shared__ float sb[OUT_C];
    for (int i = threadIdx.x; i < IN_C * OUT_C; i += blockDim.x) sW[i] = W_lin[i];
    if (threadIdx.x < OUT_C) sb[threadIdx.x] = b_lin[threadIdx.x];
    __syncthreads();

    int n = blockIdx.x * blockDim.x + threadIdx.x;
    if (n >= N) return;

    float acc[OUT_C];
    #pragma unroll
    for (int j = 0; j < OUT_C; j++) acc[j] = sb[j];

    const f4* xr = (const f4*)(x + (size_t)n * IN_C);
    #pragma unroll
    for (int k4 = 0; k4 < IN_C / 4; k4++) {
        f4 xv = __builtin_nontemporal_load(xr + k4);
        #pragma unroll
        for (int kk = 0; kk < 4; kk++) {
            const int k = k4 * 4 + kk;
            const float xs = xv[kk];
            const f4* wrow = (const f4*)(sW + k * OUT_C);
            #pragma unroll
            for (int jq = 0; jq < 4; jq++) {
                f4 wv = wrow[jq];
                acc[jq * 4 + 0] = fmaf(xs, wv[0], acc[jq * 4 + 0]);
                acc[jq * 4 + 1] = fmaf(xs, wv[1], acc[jq * 4 + 1]);
                acc[jq * 4 + 2] = fmaf(xs, wv[2], acc[jq * 4 + 2]);
                acc[jq * 4 + 3] = fmaf(xs, wv[3], acc[jq * 4 + 3]);
            }
        }
    }

    f4* hr = (f4*)(h + (size_t)n * OUT_C);
    #pragma unroll
    for (int jq = 0; jq < 4; jq++) {
        f4 o;
        o[0] = acc[jq * 4 + 0]; o[1] = acc[jq * 4 + 1];
        o[2] = acc[jq * 4 + 2]; o[3] = acc[jq * 4 + 3];
        hr[jq] = o;
    }
}

// ---------------------------------------------------------------------------
// Per-edge compute: ea transform + 32 scores (abs-trick ReLU MLP) +
// softmax (no max-shift; scores are O(1)) + scaled output.
// ---------------------------------------------------------------------------
__device__ __forceinline__ void do_edge(
    f4 H0, f4 H1, f4 H2, f4 H3,
    f4 Ea, f4 Eb,
    const float* __restrict__ sWe, const float* __restrict__ b_edge,
    const float* w1v, const float* b1u, const float* su,
    float P, float Qv, float* __restrict__ outp, bool valid)
{
    float nv[16] = {H0[0], H0[1], H0[2], H0[3], H1[0], H1[1], H1[2], H1[3],
                    H2[0], H2[1], H2[2], H2[3], H3[0], H3[1], H3[2], H3[3]};
    float ear[8] = {Ea[0], Ea[1], Ea[2], Ea[3], Eb[0], Eb[1], Eb[2], Eb[3]};

    // ea = edge_attr @ W_edge + b_edge   (float4 LDS broadcast reads)
    float ea[16];
    #pragma unroll
    for (int jq = 0; jq < 4; jq++) {
        f4 w[8];
        #pragma unroll
        for (int d = 0; d < 8; d++)
            w[d] = ((const f4*)sWe)[d * 4 + jq];
        #pragma unroll
        for (int cc = 0; cc < 4; cc++) {
            float acc = fmaf(ear[0], w[0][cc], b_edge[jq * 4 + cc]);
            #pragma unroll
            for (int d = 1; d < 8; d++)
                acc = fmaf(ear[d], w[d][cc], acc);
            ea[jq * 4 + cc] = acc;
        }
    }

    // 32 scores -> exp directly (no max-shift; |score| is O(1))
    float ex[32];
    #pragma unroll
    for (int k = 0; k < 32; k++) {
        const float cv = (k < 16) ? nv[k] : ea[k - 16];
        float acc = fmaf(P, cv, Qv);                 // s,v,v
        #pragma unroll
        for (int j = 0; j < 16; j++) {
            float t = fmaf(cv, w1v[j], b1u[j]);      // v,v,s
            acc = fmaf(fabsf(t), su[j], acc);        // |v|,s,v
        }
        ex[k] = __expf(acc);
    }

    // pairwise tree sum (depth 5)
    float s16[16];
    #pragma unroll
    for (int i = 0; i < 16; i++) s16[i] = ex[2 * i] + ex[2 * i + 1];
    float s8[8];
    #pragma unroll
    for (int i = 0; i < 8; i++) s8[i] = s16[2 * i] + s16[2 * i + 1];
    float s4[4];
    #pragma unroll
    for (int i = 0; i < 4; i++) s4[i] = s8[2 * i] + s8[2 * i + 1];
    float sum = (s4[0] + s4[1]) + (s4[2] + s4[3]);
    const float inv = __builtin_amdgcn_rcpf(sum);    // ~1ulp, fine vs 2.5e-3 thr

    if (valid) {
        float nvs[16];
        #pragma unroll
        for (int k = 0; k < 16; k++) nvs[k] = nv[k] * inv;
        f4* o = (f4*)outp;
        #pragma unroll
        for (int q = 0; q < 8; q++) {
            f4 v;
            v[0] = nvs[(q * 4 + 0) >> 1] * ex[q * 4 + 0];
            v[1] = nvs[(q * 4 + 1) >> 1] * ex[q * 4 + 1];
            v[2] = nvs[(q * 4 + 2) >> 1] * ex[q * 4 + 2];
            v[3] = nvs[(q * 4 + 3) >> 1] * ex[q * 4 + 3];
            __builtin_nontemporal_store(v, o + q);
        }
    }
}

// ---------------------------------------------------------------------------
// Kernel 2: TWO edges per thread, phase-split. All memory issued up front so
// edge1's col->gather chain hides under edge0's ~2600-cycle compute.
// ---------------------------------------------------------------------------
__global__ __launch_bounds__(256) void edge_attn_kernel(
    const float* __restrict__ edge_attr, const int* __restrict__ col,
    const float* __restrict__ h,
    const float* __restrict__ W_edge, const float* __restrict__ b_edge,
    const float* __restrict__ w1, const float* __restrict__ b1,
    const float* __restrict__ w2, const float* __restrict__ b2,
    float* __restrict__ out, int E)
{
    __shared__ float sWe[8 * OUT_C];   // 512 B
    if (threadIdx.x < 32)
        ((f4*)sWe)[threadIdx.x] = ((const f4*)W_edge)[threadIdx.x];
    __syncthreads();

    const int e0 = blockIdx.x * 512 + threadIdx.x;
    const int e1 = e0 + 256;
    const bool k0 = e0 < E, k1 = e1 < E;
    const int ce0 = k0 ? e0 : 0;
    const int ce1 = k1 ? e1 : 0;

    // ---- issue ALL memory up front ------------------------------------
    const int c0 = __builtin_nontemporal_load(col + ce0);
    const int c1 = __builtin_nontemporal_load(col + ce1);
    const f4* h0p = (const f4*)(h + (size_t)c0 * OUT_C);
    const f4* h1p = (const f4*)(h + (size_t)c1 * OUT_C);
    f4 A0 = h0p[0], A1 = h0p[1], A2 = h0p[2], A3 = h0p[3];
    f4 B0 = h1p[0], B1 = h1p[1], B2 = h1p[2], B3 = h1p[3];
    const f4* ep0 = (const f4*)(edge_attr + (size_t)ce0 * 8);
    const f4* ep1 = (const f4*)(edge_attr + (size_t)ce1 * 8);
    f4 E00 = __builtin_nontemporal_load(ep0);
    f4 E01 = __builtin_nontemporal_load(ep0 + 1);
    f4 E10 = __builtin_nontemporal_load(ep1);
    f4 E11 = __builtin_nontemporal_load(ep1 + 1);

    // ---- uniform MLP constants (overlap with VMEM latency) ------------
    float w1v[16], b1u[16], su[16];
    float P = 0.f, Qv;
    {
        float Q = b2[0];
        #pragma unroll
        for (int j = 0; j < 16; j++) {
            float w1j = w1[j];
            float b1j = b1[j];
            float sj  = 0.5f * w2[j];
            b1u[j] = b1j;
            su[j]  = sj;
            P = fmaf(w1j, sj, P);
            Q = fmaf(b1j, sj, Q);
            asm("v_mov_b32 %0, %1" : "=v"(w1v[j]) : "s"(w1j));
        }
        asm("v_mov_b32 %0, %1" : "=v"(Qv) : "s"(Q));
    }

    do_edge(A0, A1, A2, A3, E00, E01, sWe, b_edge, w1v, b1u, su, P, Qv,
            out + (size_t)e0 * 32, k0);
    do_edge(B0, B1, B2, B3, E10, E11, sWe, b_edge, w1v, b1u, su, P, Qv,
            out + (size_t)e1 * 32, k1);
}

// ---------------------------------------------------------------------------
extern "C" void kernel_launch(void* const* d_in, const int* in_sizes, int n_in,
                              void* d_out, int out_size, void* d_ws, size_t ws_size,
                              hipStream_t stream) {
    const float* x         = (const float*)d_in[0];
    const float* edge_attr = (const float*)d_in[1];
    const int*   col       = (const int*)d_in[2];
    const float* W_lin     = (const float*)d_in[3];
    const float* b_lin     = (const float*)d_in[4];
    const float* W_edge    = (const float*)d_in[5];
    const float* b_edge    = (const float*)d_in[6];
    const float* w1        = (const float*)d_in[7];
    const float* b1        = (const float*)d_in[8];
    const float* w2        = (const float*)d_in[9];
    const float* b2        = (const float*)d_in[10];
    float* out = (float*)d_out;

    const int N = in_sizes[0] / IN_C;     // 100000
    const int E = in_sizes[1] / 8;        // 1000000

    float* h = (float*)d_ws;              // N*16 floats = 6.4 MB scratch

    dim3 blk(256);
    dim3 grid1((N + 255) / 256);
    node_linear_kernel<<<grid1, blk, 0, stream>>>(x, W_lin, b_lin, h, N);

    dim3 grid2((E + 511) / 512);          // 2 edges per thread
    edge_attn_kernel<<<grid2, blk, 0, stream>>>(edge_attr, col, h,
                                                W_edge, b_edge, w1, b1, w2, b2,
                                                out, E);
}

// Round 5
// 97.040 us; speedup vs baseline: 3.8179x; 3.8179x over previous
//
#include <hip/hip_runtime.h>
#include <math.h>

#define IN_C 64
#define OUT_C 16

typedef float f4 __attribute__((ext_vector_type(4)));   // native vec for NT builtins

// ---------------------------------------------------------------------------
// Kernel 1: h = x @ W_lin + b_lin      [N,64] x [64,16] -> [N,16]
// x is single-use: non-temporal loads keep L2 clean for the edge kernel.
// ---------------------------------------------------------------------------
__global__ __launch_bounds__(256) void node_linear_kernel(
    const float* __restrict__ x, const float* __restrict__ W_lin,
    const float* __restrict__ b_lin, float* __restrict__ h, int N)
{
    __shared__ float sW[IN_C * OUT_C];   // 4 KB
    __shared__ float sb[OUT_C];
    for (int i = threadIdx.x; i < IN_C * OUT_C; i += blockDim.x) sW[i] = W_lin[i];
    if (threadIdx.x < OUT_C) sb[threadIdx.x] = b_lin[threadIdx.x];
    __syncthreads();

    int n = blockIdx.x * blockDim.x + threadIdx.x;
    if (n >= N) return;

    float acc[OUT_C];
    #pragma unroll
    for (int j = 0; j < OUT_C; j++) acc[j] = sb[j];

    const f4* xr = (const f4*)(x + (size_t)n * IN_C);
    #pragma unroll
    for (int k4 = 0; k4 < IN_C / 4; k4++) {
        f4 xv = __builtin_nontemporal_load(xr + k4);
        #pragma unroll
        for (int kk = 0; kk < 4; kk++) {
            const int k = k4 * 4 + kk;
            const float xs = xv[kk];
            const f4* wrow = (const f4*)(sW + k * OUT_C);
            #pragma unroll
            for (int jq = 0; jq < 4; jq++) {
                f4 wv = wrow[jq];
                acc[jq * 4 + 0] = fmaf(xs, wv[0], acc[jq * 4 + 0]);
                acc[jq * 4 + 1] = fmaf(xs, wv[1], acc[jq * 4 + 1]);
                acc[jq * 4 + 2] = fmaf(xs, wv[2], acc[jq * 4 + 2]);
                acc[jq * 4 + 3] = fmaf(xs, wv[3], acc[jq * 4 + 3]);
            }
        }
    }

    f4* hr = (f4*)(h + (size_t)n * OUT_C);
    #pragma unroll
    for (int jq = 0; jq < 4; jq++) {
        f4 o;
        o[0] = acc[jq * 4 + 0]; o[1] = acc[jq * 4 + 1];
        o[2] = acc[jq * 4 + 2]; o[3] = acc[jq * 4 + 3];
        hr[jq] = o;
    }
}

// ---------------------------------------------------------------------------
// Per-edge compute: ea transform + 32 scores (abs-trick ReLU MLP) +
// softmax (no max-shift; scores are O(1)) + scaled output.
// ---------------------------------------------------------------------------
__device__ __forceinline__ void do_edge(
    f4 H0, f4 H1, f4 H2, f4 H3,
    f4 Ea, f4 Eb,
    const float* __restrict__ sWe, const float* __restrict__ b_edge,
    const float* w1v, const float* b1u, const float* su,
    float P, float Qv, float* __restrict__ outp, bool valid)
{
    float nv[16] = {H0[0], H0[1], H0[2], H0[3], H1[0], H1[1], H1[2], H1[3],
                    H2[0], H2[1], H2[2], H2[3], H3[0], H3[1], H3[2], H3[3]};
    float ear[8] = {Ea[0], Ea[1], Ea[2], Ea[3], Eb[0], Eb[1], Eb[2], Eb[3]};

    // ea = edge_attr @ W_edge + b_edge   (float4 LDS broadcast reads)
    float ea[16];
    #pragma unroll
    for (int jq = 0; jq < 4; jq++) {
        f4 w[8];
        #pragma unroll
        for (int d = 0; d < 8; d++)
            w[d] = ((const f4*)sWe)[d * 4 + jq];
        #pragma unroll
        for (int cc = 0; cc < 4; cc++) {
            float acc = fmaf(ear[0], w[0][cc], b_edge[jq * 4 + cc]);
            #pragma unroll
            for (int d = 1; d < 8; d++)
                acc = fmaf(ear[d], w[d][cc], acc);
            ea[jq * 4 + cc] = acc;
        }
    }

    // 32 scores -> exp directly (no max-shift; |score| is O(1))
    float ex[32];
    #pragma unroll
    for (int k = 0; k < 32; k++) {
        const float cv = (k < 16) ? nv[k] : ea[k - 16];
        float acc = fmaf(P, cv, Qv);                 // s,v,v
        #pragma unroll
        for (int j = 0; j < 16; j++) {
            float t = fmaf(cv, w1v[j], b1u[j]);      // v,v,s
            acc = fmaf(fabsf(t), su[j], acc);        // |v|,s,v
        }
        ex[k] = __expf(acc);
    }

    // pairwise tree sum (depth 5)
    float s16[16];
    #pragma unroll
    for (int i = 0; i < 16; i++) s16[i] = ex[2 * i] + ex[2 * i + 1];
    float s8[8];
    #pragma unroll
    for (int i = 0; i < 8; i++) s8[i] = s16[2 * i] + s16[2 * i + 1];
    float s4[4];
    #pragma unroll
    for (int i = 0; i < 4; i++) s4[i] = s8[2 * i] + s8[2 * i + 1];
    float sum = (s4[0] + s4[1]) + (s4[2] + s4[3]);
    const float inv = __builtin_amdgcn_rcpf(sum);    // ~1ulp, fine vs 2.5e-3 thr

    if (valid) {
        float nvs[16];
        #pragma unroll
        for (int k = 0; k < 16; k++) nvs[k] = nv[k] * inv;
        f4* o = (f4*)outp;
        #pragma unroll
        for (int q = 0; q < 8; q++) {
            f4 v;
            v[0] = nvs[(q * 4 + 0) >> 1] * ex[q * 4 + 0];
            v[1] = nvs[(q * 4 + 1) >> 1] * ex[q * 4 + 1];
            v[2] = nvs[(q * 4 + 2) >> 1] * ex[q * 4 + 2];
            v[3] = nvs[(q * 4 + 3) >> 1] * ex[q * 4 + 3];
            o[q] = v;    // PLAIN store: L2 merges the wave's 8KB; NT store
        }                // caused 3x write amplification (round 4).
    }
}

// ---------------------------------------------------------------------------
// Kernel 2: TWO edges per thread, phase-split. All memory issued up front so
// edge1's col->gather chain hides under edge0's ~2600-cycle compute.
// ---------------------------------------------------------------------------
__global__ __launch_bounds__(256) void edge_attn_kernel(
    const float* __restrict__ edge_attr, const int* __restrict__ col,
    const float* __restrict__ h,
    const float* __restrict__ W_edge, const float* __restrict__ b_edge,
    const float* __restrict__ w1, const float* __restrict__ b1,
    const float* __restrict__ w2, const float* __restrict__ b2,
    float* __restrict__ out, int E)
{
    __shared__ float sWe[8 * OUT_C];   // 512 B
    if (threadIdx.x < 32)
        ((f4*)sWe)[threadIdx.x] = ((const f4*)W_edge)[threadIdx.x];
    __syncthreads();

    const int e0 = blockIdx.x * 512 + threadIdx.x;
    const int e1 = e0 + 256;
    const bool k0 = e0 < E, k1 = e1 < E;
    const int ce0 = k0 ? e0 : 0;
    const int ce1 = k1 ? e1 : 0;

    // ---- issue ALL memory up front ------------------------------------
    const int c0 = __builtin_nontemporal_load(col + ce0);
    const int c1 = __builtin_nontemporal_load(col + ce1);
    const f4* h0p = (const f4*)(h + (size_t)c0 * OUT_C);
    const f4* h1p = (const f4*)(h + (size_t)c1 * OUT_C);
    f4 A0 = h0p[0], A1 = h0p[1], A2 = h0p[2], A3 = h0p[3];
    f4 B0 = h1p[0], B1 = h1p[1], B2 = h1p[2], B3 = h1p[3];
    const f4* ep0 = (const f4*)(edge_attr + (size_t)ce0 * 8);
    const f4* ep1 = (const f4*)(edge_attr + (size_t)ce1 * 8);
    f4 E00 = __builtin_nontemporal_load(ep0);
    f4 E01 = __builtin_nontemporal_load(ep0 + 1);
    f4 E10 = __builtin_nontemporal_load(ep1);
    f4 E11 = __builtin_nontemporal_load(ep1 + 1);

    // ---- uniform MLP constants (overlap with VMEM latency) ------------
    float w1v[16], b1u[16], su[16];
    float P = 0.f, Qv;
    {
        float Q = b2[0];
        #pragma unroll
        for (int j = 0; j < 16; j++) {
            float w1j = w1[j];
            float b1j = b1[j];
            float sj  = 0.5f * w2[j];
            b1u[j] = b1j;
            su[j]  = sj;
            P = fmaf(w1j, sj, P);
            Q = fmaf(b1j, sj, Q);
            asm("v_mov_b32 %0, %1" : "=v"(w1v[j]) : "s"(w1j));
        }
        asm("v_mov_b32 %0, %1" : "=v"(Qv) : "s"(Q));
    }

    do_edge(A0, A1, A2, A3, E00, E01, sWe, b_edge, w1v, b1u, su, P, Qv,
            out + (size_t)e0 * 32, k0);
    do_edge(B0, B1, B2, B3, E10, E11, sWe, b_edge, w1v, b1u, su, P, Qv,
            out + (size_t)e1 * 32, k1);
}

// ---------------------------------------------------------------------------
extern "C" void kernel_launch(void* const* d_in, const int* in_sizes, int n_in,
                              void* d_out, int out_size, void* d_ws, size_t ws_size,
                              hipStream_t stream) {
    const float* x         = (const float*)d_in[0];
    const float* edge_attr = (const float*)d_in[1];
    const int*   col       = (const int*)d_in[2];
    const float* W_lin     = (const float*)d_in[3];
    const float* b_lin     = (const float*)d_in[4];
    const float* W_edge    = (const float*)d_in[5];
    const float* b_edge    = (const float*)d_in[6];
    const float* w1        = (const float*)d_in[7];
    const float* b1        = (const float*)d_in[8];
    const float* w2        = (const float*)d_in[9];
    const float* b2        = (const float*)d_in[10];
    float* out = (float*)d_out;

    const int N = in_sizes[0] / IN_C;     // 100000
    const int E = in_sizes[1] / 8;        // 1000000

    float* h = (float*)d_ws;              // N*16 floats = 6.4 MB scratch

    dim3 blk(256);
    dim3 grid1((N + 255) / 256);
    node_linear_kernel<<<grid1, blk, 0, stream>>>(x, W_lin, b_lin, h, N);

    dim3 grid2((E + 511) / 512);          // 2 edges per thread
    edge_attn_kernel<<<grid2, blk, 0, stream>>>(edge_attr, col, h,
                                                W_edge, b_edge, w1, b1, w2, b2,
                                                out, E);
}

// Round 6
// 79.648 us; speedup vs baseline: 4.6515x; 1.2184x over previous
//
#include <hip/hip_runtime.h>
#include <math.h>

#define IN_C 64
#define OUT_C 16

typedef float f4 __attribute__((ext_vector_type(4)));
typedef float f2 __attribute__((ext_vector_type(2)));

// ---------------------------------------------------------------------------
// Kernel 1: h = x @ W_lin + b_lin      [N,64] x [64,16] -> [N,16]
// ---------------------------------------------------------------------------
__global__ __launch_bounds__(256) void node_linear_kernel(
    const float* __restrict__ x, const float* __restrict__ W_lin,
    const float* __restrict__ b_lin, float* __restrict__ h, int N)
{
    __shared__ float sW[IN_C * OUT_C];   // 4 KB
    __shared__ float sb[OUT_C];
    for (int i = threadIdx.x; i < IN_C * OUT_C; i += blockDim.x) sW[i] = W_lin[i];
    if (threadIdx.x < OUT_C) sb[threadIdx.x] = b_lin[threadIdx.x];
    __syncthreads();

    int n = blockIdx.x * blockDim.x + threadIdx.x;
    if (n >= N) return;

    float acc[OUT_C];
    #pragma unroll
    for (int j = 0; j < OUT_C; j++) acc[j] = sb[j];

    const f4* xr = (const f4*)(x + (size_t)n * IN_C);
    #pragma unroll
    for (int k4 = 0; k4 < IN_C / 4; k4++) {
        f4 xv = __builtin_nontemporal_load(xr + k4);
        #pragma unroll
        for (int kk = 0; kk < 4; kk++) {
            const int k = k4 * 4 + kk;
            const float xs = xv[kk];
            const f4* wrow = (const f4*)(sW + k * OUT_C);
            #pragma unroll
            for (int jq = 0; jq < 4; jq++) {
                f4 wv = wrow[jq];
                acc[jq * 4 + 0] = fmaf(xs, wv[0], acc[jq * 4 + 0]);
                acc[jq * 4 + 1] = fmaf(xs, wv[1], acc[jq * 4 + 1]);
                acc[jq * 4 + 2] = fmaf(xs, wv[2], acc[jq * 4 + 2]);
                acc[jq * 4 + 3] = fmaf(xs, wv[3], acc[jq * 4 + 3]);
            }
        }
    }

    f4* hr = (f4*)(h + (size_t)n * OUT_C);
    #pragma unroll
    for (int jq = 0; jq < 4; jq++) {
        f4 o;
        o[0] = acc[jq * 4 + 0]; o[1] = acc[jq * 4 + 1];
        o[2] = acc[jq * 4 + 2]; o[3] = acc[jq * 4 + 3];
        hr[jq] = o;
    }
}

// ---------------------------------------------------------------------------
// Kernel 2: EIGHT lanes per edge. Lane sub owns outputs [4*sub .. 4*sub+3]
// and therefore scores k = 4*sub+q (k<16 -> nv[k], k>=16 -> ea[k-16]).
// All global accesses are wave-contiguous: stores are 1 KB/instr.
// ---------------------------------------------------------------------------
__global__ __launch_bounds__(256) void edge_attn8_kernel(
    const float* __restrict__ edge_attr, const int* __restrict__ col,
    const float* __restrict__ h,
    const float* __restrict__ W_edge, const float* __restrict__ b_edge,
    const float* __restrict__ w1, const float* __restrict__ b1,
    const float* __restrict__ w2, const float* __restrict__ b2,
    float* __restrict__ out, int E)
{
    __shared__ float sWe[8 * OUT_C];   // [d][j] row-major, 512 B
    __shared__ float sbe[OUT_C];
    if (threadIdx.x < 32)
        ((f4*)sWe)[threadIdx.x] = ((const f4*)W_edge)[threadIdx.x];
    if (threadIdx.x >= 32 && threadIdx.x < 36)
        ((f4*)sbe)[threadIdx.x - 32] = ((const f4*)b_edge)[threadIdx.x - 32];
    __syncthreads();

    const int tid  = blockIdx.x * 256 + threadIdx.x;
    const int e    = tid >> 3;
    if (e >= E) return;
    const int lane = threadIdx.x & 63;
    const int sub  = lane & 7;

    // ---- coalesced loads ---------------------------------------------
    const int c = col[e];                                   // group-broadcast
    const f2* hp = (const f2*)(h + (size_t)c * OUT_C);
    f2 nv2 = hp[sub];                                       // nv[2sub], nv[2sub+1]

    const f4* ep = (const f4*)(edge_attr + (size_t)e * 8);  // full 32B row/lane
    f4 eaA = ep[0], eaB = ep[1];
    float ear[8] = {eaA[0], eaA[1], eaA[2], eaA[3],
                    eaB[0], eaB[1], eaB[2], eaB[3]};

    // ---- uniform MLP constants ----------------------------------------
    float w1v[16], b1u[16], su[16];
    float P = 0.f, Qv;
    {
        float Q = b2[0];
        #pragma unroll
        for (int j = 0; j < 16; j++) {
            float a = w1[j], b = b1[j], s = 0.5f * w2[j];
            b1u[j] = b; su[j] = s;
            P = fmaf(a, s, P);
            Q = fmaf(b, s, Q);
            asm("v_mov_b32 %0, %1" : "=v"(w1v[j]) : "s"(a));
        }
        asm("v_mov_b32 %0, %1" : "=v"(Qv) : "s"(Q));
    }

    // ---- this lane's ea pair: columns 2sub, 2sub+1 --------------------
    const f2* sWe2 = (const f2*)sWe;   // [d][8 pairs]
    const f2* sbe2 = (const f2*)sbe;
    f2 bpair = sbe2[sub];
    float eax = bpair[0], eay = bpair[1];
    #pragma unroll
    for (int d = 0; d < 8; d++) {
        f2 w = sWe2[d * 8 + sub];      // 8 distinct banks, group-broadcast
        eax = fmaf(ear[d], w[0], eax);
        eay = fmaf(ear[d], w[1], eay);
    }

    // ---- assemble this lane's score inputs cv[0..3] via shuffles ------
    // producer lanes srcA/srcB hold the needed float2 pair for BOTH halves
    const int srcA = (lane & 56) | (2 * (sub & 3));
    const int srcB = srcA | 1;
    float cv[4];
    {
        float a0 = __shfl(nv2[0], srcA, 64), a1 = __shfl(nv2[1], srcA, 64);
        float a2 = __shfl(nv2[0], srcB, 64), a3 = __shfl(nv2[1], srcB, 64);
        float b0 = __shfl(eax,    srcA, 64), b1s = __shfl(eay,   srcA, 64);
        float b2s = __shfl(eax,   srcB, 64), b3 = __shfl(eay,    srcB, 64);
        const bool lo = (sub < 4);
        cv[0] = lo ? a0 : b0;   cv[1] = lo ? a1 : b1s;
        cv[2] = lo ? a2 : b2s;  cv[3] = lo ? a3 : b3;
    }

    // ---- 4 scores -> exp (no max-shift; scores are O(1)) --------------
    float ex[4];
    #pragma unroll
    for (int q = 0; q < 4; q++) {
        float acc = fmaf(P, cv[q], Qv);
        #pragma unroll
        for (int j = 0; j < 16; j++) {
            float t = fmaf(cv[q], w1v[j], b1u[j]);
            acc = fmaf(fabsf(t), su[j], acc);
        }
        ex[q] = __expf(acc);
    }

    // ---- softmax denominator over the 8-lane group --------------------
    float psum = (ex[0] + ex[1]) + (ex[2] + ex[3]);
    psum += __shfl_xor(psum, 1, 64);
    psum += __shfl_xor(psum, 2, 64);
    psum += __shfl_xor(psum, 4, 64);
    const float inv = __builtin_amdgcn_rcpf(psum);

    // ---- output: out[e][4sub+q] = nv[(4sub+q)>>1] * attn ---------------
    f4 o;
    o[0] = nv2[0] * ex[0] * inv;
    o[1] = nv2[0] * ex[1] * inv;
    o[2] = nv2[1] * ex[2] * inv;
    o[3] = nv2[1] * ex[3] * inv;
    ((f4*)(out + (size_t)e * 32))[sub] = o;    // wave-contiguous 1 KB store
}

// ---------------------------------------------------------------------------
extern "C" void kernel_launch(void* const* d_in, const int* in_sizes, int n_in,
                              void* d_out, int out_size, void* d_ws, size_t ws_size,
                              hipStream_t stream) {
    const float* x         = (const float*)d_in[0];
    const float* edge_attr = (const float*)d_in[1];
    const int*   col       = (const int*)d_in[2];
    const float* W_lin     = (const float*)d_in[3];
    const float* b_lin     = (const float*)d_in[4];
    const float* W_edge    = (const float*)d_in[5];
    const float* b_edge    = (const float*)d_in[6];
    const float* w1        = (const float*)d_in[7];
    const float* b1        = (const float*)d_in[8];
    const float* w2        = (const float*)d_in[9];
    const float* b2        = (const float*)d_in[10];
    float* out = (float*)d_out;

    const int N = in_sizes[0] / IN_C;     // 100000
    const int E = in_sizes[1] / 8;        // 1000000

    float* h = (float*)d_ws;              // N*16 floats = 6.4 MB scratch

    dim3 blk(256);
    dim3 grid1((N + 255) / 256);
    node_linear_kernel<<<grid1, blk, 0, stream>>>(x, W_lin, b_lin, h, N);

    // 8 threads per edge
    long long total = (long long)E * 8;
    dim3 grid2((unsigned)((total + 255) / 256));
    edge_attn8_kernel<<<grid2, blk, 0, stream>>>(edge_attr, col, h,
                                                 W_edge, b_edge, w1, b1, w2, b2,
                                                 out, E);
}